// Round 15
// baseline (1746.288 us; speedup 1.0000x reference)
//
#include <hip/hip_runtime.h>
#include <hip/hip_fp8.h>
#include <stdint.h>

#define EPS 1e-8f

constexpr int C  = 256;     // channels (K dim)
constexpr int HW = 16384;   // pixels per image (M and N dims)
constexpr int BM = 128;     // block M tile (2 wm-waves x 2 mi-tiles x 32 rows)
constexpr int NG = 1024;    // n-group width per block (16 q-steps of 64 cols)

typedef __attribute__((ext_vector_type(16))) float floatx16;
typedef __attribute__((ext_vector_type(8)))  int  int8v;
typedef __attribute__((ext_vector_type(4)))  int  int4v;
typedef unsigned char u8;
typedef unsigned int u32;
typedef unsigned long long u64;

__device__ inline u8 f2fp8(float x) {   // OCP e4m3 (gfx950 HW cvt)
    __hip_fp8_e4m3 h(x);
    return h.__x;
}

// pack 4 floats -> 4 fp8 bytes (little-endian order a,b,c,d)
__device__ inline u32 pk4(float va, float vb, float vc, float vd) {
#if __has_builtin(__builtin_amdgcn_cvt_pk_fp8_f32)
    u32 w = __builtin_amdgcn_cvt_pk_fp8_f32(va, vb, 0, false);   // bytes 0,1
    w = __builtin_amdgcn_cvt_pk_fp8_f32(vc, vd, w, true);        // bytes 2,3
    return w;
#else
    return (u32)f2fp8(va) | ((u32)f2fp8(vb) << 8) |
           ((u32)f2fp8(vc) << 16) | ((u32)f2fp8(vd) << 24);
#endif
}

__device__ inline float fc(const float4& f, int j) {
    return j == 0 ? f.x : j == 1 ? f.y : j == 2 ? f.z : f.w;
}

__device__ inline int8v ld32(const u8* p) {    // 32B/lane = one MX fragment slice
    int4v lo = *(const int4v*)p;
    int4v hi = *(const int4v*)(p + 16);
    return __builtin_shufflevector(lo, hi, 0, 1, 2, 3, 4, 5, 6, 7);
}

// unit scales (e8m0 127 -> x1.0) make the scaled MFMA a plain fp8 matmul at 2x rate
#define MFMA_SC(A, B, Cop) __builtin_amdgcn_mfma_scale_f32_32x32x64_f8f6f4( \
    (A), (B), (Cop), 0, 0, 0, 0x7F7F7F7F, 0, 0x7F7F7F7F)

// ---------------------------------------------------------------------------
// PREP (R14 v4 read structure — verified): 512 thr, 32 px x 256 ch per block,
// 512 blocks. NEW fragment layout for mfma_scale 32x32x64: slab (g = p>>5,
// kb = cc>>6) is 2048B; lane l holds A[row = g*32 + (l&31)][k = kb*64 +
// (l>>5)*32 + j], j = 0..31 consecutive bytes (each lane = exactly one MX
// 32-element scale block). Thread (pxq=tid&7, tc=tid>>3): pixels pxq*4..+4,
// channels tc*4..+4 -> kb = tc>>4, lanehalf = (tc>>3)&1, byte = (tc&7)*4;
// one u32 store per pixel. b normalized, a raw. Zeroes packed/out.
__global__ __launch_bounds__(512) void prep_kernel(const float* __restrict__ a,
                                                   const float* __restrict__ b,
                                                   float* __restrict__ sumsq_a,
                                                   float* __restrict__ sumsq_b,
                                                   u8* __restrict__ aF, u8* __restrict__ bF,
                                                   u64* __restrict__ packed,
                                                   float* __restrict__ out) {
    __shared__ float red[32][65];    // [pixel][tc] (65: bank-spread)
    __shared__ float invb_sh[32];
    const int tid = threadIdx.x;
    const int pxq = tid & 7, tc = tid >> 3;
    const int p0 = blockIdx.x * 32, pb = pxq * 4;
    const int kb = tc >> 4, lh = (tc >> 3) & 1, byt = (tc & 7) * 4;

    if (tid < 32) packed[blockIdx.x * 32 + tid] = 0;
    if (blockIdx.x == 0 && tid == 0) *out = 0.f;

    // ---- b: 4 channel rows x 4 pixels + per-pixel partial sumsq
    float4 bv[4];
    float ss0 = 0.f, ss1 = 0.f, ss2 = 0.f, ss3 = 0.f;
    #pragma unroll
    for (int i = 0; i < 4; ++i) {
        bv[i] = *(const float4*)&b[(size_t)(tc * 4 + i) * HW + p0 + pb];
        ss0 += bv[i].x * bv[i].x; ss1 += bv[i].y * bv[i].y;
        ss2 += bv[i].z * bv[i].z; ss3 += bv[i].w * bv[i].w;
    }
    red[pb + 0][tc] = ss0; red[pb + 1][tc] = ss1;
    red[pb + 2][tc] = ss2; red[pb + 3][tc] = ss3;
    __syncthreads();
    if (tid < 32) {
        float B = 0.f;
        #pragma unroll
        for (int k = 0; k < 64; ++k) B += red[tid][k];
        sumsq_b[p0 + tid] = B;
        invb_sh[tid] = 1.0f / (sqrtf(B + EPS) + EPS);
    }
    __syncthreads();

    #pragma unroll
    for (int j = 0; j < 4; ++j) {
        int p = p0 + pb + j;
        float inv = invb_sh[pb + j];
        u32 w = pk4(fc(bv[0], j) * inv, fc(bv[1], j) * inv,
                    fc(bv[2], j) * inv, fc(bv[3], j) * inv);
        size_t off = ((size_t)(blockIdx.x * 4 + kb) << 11)
                   + (u32)(((p & 31) + lh * 32) * 32 + byt);
        *(u32*)(bF + off) = w;
    }

    // ---- a: raw fragments + sumsq partials
    float4 av[4];
    ss0 = ss1 = ss2 = ss3 = 0.f;
    #pragma unroll
    for (int i = 0; i < 4; ++i) {
        av[i] = *(const float4*)&a[(size_t)(tc * 4 + i) * HW + p0 + pb];
        ss0 += av[i].x * av[i].x; ss1 += av[i].y * av[i].y;
        ss2 += av[i].z * av[i].z; ss3 += av[i].w * av[i].w;
    }
    #pragma unroll
    for (int j = 0; j < 4; ++j) {
        int p = p0 + pb + j;
        u32 w = pk4(fc(av[0], j), fc(av[1], j), fc(av[2], j), fc(av[3], j));
        size_t off = ((size_t)(blockIdx.x * 4 + kb) << 11)
                   + (u32)(((p & 31) + lh * 32) * 32 + byt);
        *(u32*)(aF + off) = w;
    }
    red[pb + 0][tc] = ss0; red[pb + 1][tc] = ss1;
    red[pb + 2][tc] = ss2; red[pb + 3][tc] = ss3;
    __syncthreads();
    if (tid < 32) {
        float A = 0.f;
        #pragma unroll
        for (int k = 0; k < 64; ++k) A += red[tid][k];
        sumsq_a[p0 + tid] = A;
    }
}

// ---------------------------------------------------------------------------
// G: fused GEMM + argmax on mfma_scale_f32_32x32x64_f8f6f4 (unit scales =
// plain fp8 at ~2x the 16x16x32 rate; instruction floor 29 µs vs 60).
// Block 256 thr = 2wm x 2wn waves; wave tile 64 rows (2 mi-tiles of 32) x
// 32 cols; N-loop over 16 steps of 64 cols (NG=1024 — R14 showed NG=512
// regresses). A register-resident (Afr[2][4] int8v = 64 VGPR). B double-
// buffered distance-1 (per-step matrix work = 8 MFMA x ~69 SIMD-cyc = 550
// cyc >> L2 latency, so depth 1 suffices at 2 waves/SIMD; total ~224 regs).
// Per-step acc init folded into the C operand of the first MFMA (BIAS=+64).
// Biased-key argmax: key = (bits & ~31) | (31-qt); v_max_u32 running best.
// C/D layout 32x32: col = lane&31, row = (r&3)+8*(r>>2)+4*(lane>>5).
__global__ __launch_bounds__(256, 2) void gemm_argmax(const u8* __restrict__ aF,
                                                      const u8* __restrict__ bF,
                                                      u64* __restrict__ packed) {
    const int tid = threadIdx.x;
    const int w = tid >> 6, lane = tid & 63;
    const int l31 = lane & 31, lh = lane >> 5;
    const int wm = w >> 1, wn = w & 1;

    const u32 bid = blockIdx.x;
    const u32 ng = bid & 15;         // n-group
    const u32 mt = bid >> 4;         // 0..127 M tile
    const int p0 = (int)mt * BM;

    u32 maskv;                       // 0xFFFFFFE0 in a VGPR -> v_and_or_b32 fusion
    asm("v_mov_b32 %0, 0xFFFFFFE0" : "=v"(maskv));

    // A resident: groups g = mt*4 + wm*2 + mi, k-blocks kb 0..3
    int8v Afr[2][4];
    #pragma unroll
    for (int mi = 0; mi < 2; ++mi)
        #pragma unroll
        for (int kb = 0; kb < 4; ++kb)
            Afr[mi][kb] = ld32(aF + ((size_t)((mt * 4 + wm * 2 + mi) * 4 + kb) << 11)
                                  + (u32)lane * 32);

    // B: col-group for step qt: gq = ng*32 + qt*2 + wn; slab (gq*4+kb)*2048
    const u8* gB = bF + ((size_t)((ng * 32 + wn) * 4) << 11) + (u32)lane * 32;
    // step stride: 2 groups * 4 kb * 2048 = 16384 bytes

    int8v Bfr[2][4];
    #pragma unroll
    for (int kb = 0; kb < 4; ++kb)
        Bfr[0][kb] = ld32(gB + (u32)kb * 2048u);

    floatx16 BIAS;
    #pragma unroll
    for (int r = 0; r < 16; ++r) BIAS[r] = 64.0f;

    u32 bestk[2][16] = {};           // biased keys all > 0

    for (int qt = 0; qt < 16; ++qt) {
        const int cur = qt & 1, nxt = cur ^ 1;
        const u32 nq = (u32)(qt + 1 < 16 ? qt + 1 : 15);
        #pragma unroll
        for (int kb = 0; kb < 4; ++kb)
            Bfr[nxt][kb] = ld32(gB + nq * 16384u + (u32)kb * 2048u);

        floatx16 acc[2];
        #pragma unroll
        for (int mi = 0; mi < 2; ++mi) {
            acc[mi] = MFMA_SC(Afr[mi][0], Bfr[cur][0], BIAS);
            #pragma unroll
            for (int kb = 1; kb < 4; ++kb)
                acc[mi] = MFMA_SC(Afr[mi][kb], Bfr[cur][kb], acc[mi]);
        }

        const u32 code = 31u - (u32)qt;      // larger code = smaller q (tie -> first)
        #pragma unroll
        for (int mi = 0; mi < 2; ++mi)
            #pragma unroll
            for (int r = 0; r < 16; ++r) {
                u32 key = (__float_as_uint(acc[mi][r]) & maskv) | code;
                bestk[mi][r] = bestk[mi][r] > key ? bestk[mi][r] : key;
            }
    }

    // epilogue: decode q, pack u64, shuffle-reduce cols (within 32-half),
    // 2 atomics per (mi,r) per wave (lanes 0 and 32: rows r0 and r0+4).
    const u32 qcol = ng * 1024u + (u32)wn * 32u + (u32)l31;
    #pragma unroll
    for (int mi = 0; mi < 2; ++mi)
        #pragma unroll
        for (int r = 0; r < 16; ++r) {
            u32 k = bestk[mi][r];
            u32 qt_ = 31u - (k & 31u);
            u32 q = qcol + qt_ * 64u;
            u64 pk = ((u64)(k & 0xFFFFFFE0u) << 32) | (u64)(0xFFFFFFFFu - q);
            #pragma unroll
            for (int d = 1; d < 32; d <<= 1) {
                u64 o = __shfl_xor((unsigned long long)pk, d);
                pk = o > pk ? o : pk;
            }
            if (l31 == 0) {
                int row_local = (r & 3) + 8 * (r >> 2) + 4 * lh;
                atomicMax(&packed[p0 + wm * 64 + mi * 32 + row_local], pk);
            }
        }
}

// ---------------------------------------------------------------------------
// L: loss from the argmax's own similarity value (no gather).
// High 32 bits of packed = float bits of (s + 64) with low 5 bits zeroed.
__global__ void loss_kernel(const u64* __restrict__ packed,
                            const float* __restrict__ sumsq_a, const float* __restrict__ sumsq_b,
                            float* __restrict__ out) {
    int p = blockIdx.x * 256 + threadIdx.x;
    u64 pk = packed[p];
    float s = __uint_as_float((u32)(pk >> 32)) - 64.0f;
    u32 q = 0xFFFFFFFFu - (u32)(pk & 0xFFFFFFFFull);
    float A = sumsq_a[p], B = sumsq_b[q];
    float dot = s * (sqrtf(B + EPS) + EPS);
    float cossim = dot / ((sqrtf(A) + EPS) * (sqrtf(B) + EPS));
    float v = (1.0f - cossim) * (1.0f / (float)HW);
    #pragma unroll
    for (int d = 1; d < 64; d <<= 1) v += __shfl_xor(v, d);
    if ((threadIdx.x & 63) == 0) atomicAdd(out, v);
}

// ---------------------------------------------------------------------------
extern "C" void kernel_launch(void* const* d_in, const int* in_sizes, int n_in,
                              void* d_out, int out_size, void* d_ws, size_t ws_size,
                              hipStream_t stream) {
    const float* a = (const float*)d_in[0];
    const float* b = (const float*)d_in[1];
    float* out = (float*)d_out;
    char* ws = (char*)d_ws;

    u8*    aF      = (u8*)ws;                                    // 4 MB
    u8*    bF      = (u8*)(ws + (size_t)4 * 1024 * 1024);        // 4 MB
    float* sumsq_a = (float*)(ws + (size_t)8 * 1024 * 1024);     // 64 KB
    float* sumsq_b = sumsq_a + HW;
    u64*   packed  = (u64*)(sumsq_b + HW);                       // 128 KB

    prep_kernel<<<dim3(HW / 32), 512, 0, stream>>>(a, b, sumsq_a, sumsq_b, aF, bF, packed, out);
    gemm_argmax<<<dim3((HW / BM) * (HW / NG)), 256, 0, stream>>>(aF, bF, packed);
    loss_kernel<<<dim3(HW / 256), 256, 0, stream>>>(packed, sumsq_a, sumsq_b, out);
}